// Round 15
// baseline (73.901 us; speedup 1.0000x reference)
//
#include <hip/hip_runtime.h>
#include <math.h>

#define BATCH 4
#define NN    12288
#define CIN   3
#define NC    4096
#define NG    12
#define NB    128
#define HSTR  9                    // k_mscan 8-channel scan stride
#define CPB   48                   // chunks per batch = NN/256
#define PSZ   (CIN * 4 * NB * 2)   // dense partial per hist block = 3072 floats

// ws float-offsets
#define SC_OFF 0                              // per group: scale, amin [NG*2]
#define P_OFF  64                             // partials [BATCH*CPB][PSZ]
#define H2_OFF (P_OFF + BATCH * CPB * PSZ)    // scanned hist [NG*4][NB*8]

// ---------- kernel 1: fused coalesced stats + consecutive-node LDS hist ----
// BATCH*CPB = 192 blocks x 256 thr; block = (batch b, 256 contiguous nodes).
// Stats: each block re-reads its batch row coalesced (L2-hot, ~0.3us total),
// tracking 3 per-channel min/max pairs via a static 3-way branch (no dynamic
// register indexing). Hist: 8 LDS atomics/node, dense 3 KB partial out.
__launch_bounds__(256)
__global__ void k_hist(const float* __restrict__ spikes,
                       const float* __restrict__ theta,
                       float* __restrict__ ws) {
    __shared__ float lh[CIN * 4 * NB * 3];    // 4608 floats
    __shared__ float sred[6][4];              // {mn0,mn1,mn2,mx0,mx1,mx2} x wave
    __shared__ float uSc[3], uAm[3];

    int blk = blockIdx.x, b = blk / CPB, chunk = blk % CPB;
    int tid = threadIdx.x, lane = tid & 63, w = tid >> 6;
    #pragma unroll
    for (int q = 0; q < 18; ++q) lh[tid + q * 256] = 0.f;

    // ---- stats phase: whole batch row, coalesced float4 ----
    const float4* row = (const float4*)(spikes + b * NN);
    float mn0 = 1e30f, mn1 = 1e30f, mn2 = 1e30f;
    float mx0 = -1e30f, mx1 = -1e30f, mx2 = -1e30f;
    #pragma unroll
    for (int q = 0; q < 12; ++q) {
        int f = tid + q * 256;                // float4 index < 3072
        float4 v4 = row[f];
        int r = f % 3;                        // channel of elem j=0 (4 = 1 mod 3)
        if (r == 0) {          // x->c0 y->c1 z->c2 w->c0
            mn0 = fminf(mn0, fminf(v4.x, v4.w)); mx0 = fmaxf(mx0, fmaxf(v4.x, v4.w));
            mn1 = fminf(mn1, v4.y);              mx1 = fmaxf(mx1, v4.y);
            mn2 = fminf(mn2, v4.z);              mx2 = fmaxf(mx2, v4.z);
        } else if (r == 1) {   // x->c1 y->c2 z->c0 w->c1
            mn1 = fminf(mn1, fminf(v4.x, v4.w)); mx1 = fmaxf(mx1, fmaxf(v4.x, v4.w));
            mn2 = fminf(mn2, v4.y);              mx2 = fmaxf(mx2, v4.y);
            mn0 = fminf(mn0, v4.z);              mx0 = fmaxf(mx0, v4.z);
        } else {               // x->c2 y->c0 z->c1 w->c2
            mn2 = fminf(mn2, fminf(v4.x, v4.w)); mx2 = fmaxf(mx2, fmaxf(v4.x, v4.w));
            mn0 = fminf(mn0, v4.y);              mx0 = fmaxf(mx0, v4.y);
            mn1 = fminf(mn1, v4.z);              mx1 = fmaxf(mx1, v4.z);
        }
    }
    #pragma unroll
    for (int off = 32; off; off >>= 1) {
        mn0 = fminf(mn0, __shfl_down(mn0, off)); mx0 = fmaxf(mx0, __shfl_down(mx0, off));
        mn1 = fminf(mn1, __shfl_down(mn1, off)); mx1 = fmaxf(mx1, __shfl_down(mx1, off));
        mn2 = fminf(mn2, __shfl_down(mn2, off)); mx2 = fmaxf(mx2, __shfl_down(mx2, off));
    }
    if (lane == 0) {
        sred[0][w] = mn0; sred[1][w] = mn1; sred[2][w] = mn2;
        sred[3][w] = mx0; sred[4][w] = mx1; sred[5][w] = mx2;
    }
    __syncthreads();                           // also covers lh zeroing
    if (tid < 3) {                             // one thread per channel
        float m0 = fminf(fminf(sred[tid][0], sred[tid][1]),
                         fminf(sred[tid][2], sred[tid][3]));
        float m1 = fmaxf(fmaxf(sred[tid + 3][0], sred[tid + 3][1]),
                         fmaxf(sred[tid + 3][2], sred[tid + 3][3]));
        float scale = 0.25f / fmaxf(m1 - m0, 1e-6f);
        uSc[tid] = scale;
        uAm[tid] = m0 * scale;
        if (chunk == 0) {                      // publish for k_mscan / k_apply
            ws[SC_OFF + (b * CIN + tid) * 2]     = scale;
            ws[SC_OFF + (b * CIN + tid) * 2 + 1] = m0 * scale;
        }
    }
    __syncthreads();

    // ---- hist phase: own node, coalesced ----
    int r = chunk * 256 + tid;                // node within batch, < NN
    int v = b * NN + r;
    int c = r % 3;
    float scale = uSc[c], amin = uAm[c];
    float a = spikes[v] * scale;              // coalesced, L1-hot
    int bb = (int)((a - amin) * (4.0f * NB));
    bb = bb < 0 ? 0 : (bb > NB - 1 ? NB - 1 : bb);
    float4 th = ((const float4*)theta)[v];    // coalesced
    float thv[4] = {th.x, th.y, th.z, th.w};
    #pragma unroll
    for (int d = 0; d < 4; ++d) {
        float sth, cth; __sincosf(thv[d], &sth, &cth);
        float* h = lh + ((c * 4 + d) * NB + bb) * 3;
        atomicAdd(h + 0, sth);
        atomicAdd(h + 1, cth);
    }
    __syncthreads();

    float* P = ws + P_OFF + (size_t)blk * PSZ;
    #pragma unroll
    for (int q = 0; q < 12; ++q) {
        int o = tid + q * 256;                // ((c*4+d)*NB+bb)*2 + ch
        P[o] = lh[(o >> 1) * 3 + (o & 1)];
    }
}

// ---------- kernel 2: per (g,d): merge CPB partials, derive 8 ch, scan -----
__launch_bounds__(256)
__global__ void k_mscan(float* __restrict__ ws) {
    __shared__ float raw[256];
    __shared__ float lh[NB * HSTR];           // 1152
    int gd = blockIdx.x, g = gd >> 2, d = gd & 3;
    int b = g / CIN, c = g % CIN;
    int tid = threadIdx.x, lane = tid & 63, w = tid >> 6;

    // partials of batch b, slice (c,d): contiguous 256-float runs
    const float* Pg = ws + P_OFF + (size_t)(b * CPB) * PSZ + (c * 4 + d) * (NB * 2);
    float s = 0.f;
    #pragma unroll 8
    for (int p = 0; p < CPB; ++p) s += Pg[(size_t)p * PSZ + tid];
    raw[tid] = s;
    __syncthreads();

    float amin = ws[SC_OFF + g * 2 + 1];
    if (tid < NB) {
        float Ss = raw[tid * 2], Sc = raw[tid * 2 + 1];
        float abar = amin + ((float)tid + 0.5f) * (0.25f / (float)NB);
        float sa, ca; __sincosf(abar, &sa, &ca);
        float c0 = fmaf(ca, Ss,  sa * Sc);    // ~ sum sin(th + a)
        float c1 = fmaf(ca, Sc, -sa * Ss);    // ~ sum cos(th + a)
        float c4 = fmaf(ca, Ss, -sa * Sc);    // ~ sum sin(th - a)
        float c5 = fmaf(ca, Sc,  sa * Ss);    // ~ sum cos(th - a)
        float* L = lh + tid * HSTR;
        L[0] = c0;        L[1] = c1;
        L[2] = abar * c0; L[3] = abar * c1;
        L[4] = c4;        L[5] = c5;
        L[6] = abar * c4; L[7] = abar * c5;
    }
    __syncthreads();

    // inclusive scan over 128 buckets; 4 waves x 2 channels, 2 buckets/lane
    #pragma unroll
    for (int p = 0; p < 2; ++p) {
        int ch = w * 2 + p;
        float x0 = lh[(lane * 2 + 0) * HSTR + ch];
        float x1 = lh[(lane * 2 + 1) * HSTR + ch];
        float i0 = x0, i1 = i0 + x1;
        float incl = i1;
        #pragma unroll
        for (int off = 1; off < 64; off <<= 1) {
            float o = __shfl_up(incl, off);
            if (lane >= off) incl += o;
        }
        float ebt = incl - i1;
        lh[(lane * 2 + 0) * HSTR + ch] = ebt + i0;
        lh[(lane * 2 + 1) * HSTR + ch] = ebt + i1;
    }
    __syncthreads();

    float* H2 = ws + H2_OFF + (size_t)gd * (NB * 8);
    #pragma unroll
    for (int q = 0; q < 4; ++q) {
        int o = tid + q * 256;
        H2[o] = lh[(o >> 3) * HSTR + (o & 7)];
    }
}

// ---------- kernel 3: contiguous nodes, LDS-staged H2, fused epilogue ------
__launch_bounds__(256)
__global__ void k_apply(const float* __restrict__ spikes,
                        const float* __restrict__ theta,
                        const float* __restrict__ gamma,
                        const float* __restrict__ ws,
                        float* __restrict__ out) {
    __shared__ __align__(16) float lH[CIN * 4 * NB * 8];   // 48 KB
    int v = blockIdx.x * 256 + threadIdx.x;   // node (blocks don't straddle b)
    int b = v / NN;

    const float4* src = (const float4*)(ws + H2_OFF + (size_t)b * (CIN * 4 * NB * 8));
    float4* dst = (float4*)lH;
    #pragma unroll
    for (int q = 0; q < 12; ++q) {
        int i = threadIdx.x + q * 256;        // < 3072
        dst[i] = src[i];
    }
    __syncthreads();

    int r = v - b * NN;
    int c = r % 3;
    int g = b * CIN + c;
    float scale = ws[SC_OFF + g * 2], amin = ws[SC_OFF + g * 2 + 1];
    float a = spikes[v] * scale;
    int bb = (int)((a - amin) * (4.0f * NB));
    bb = bb < 0 ? 0 : (bb > NB - 1 ? NB - 1 : bb);
    float sa, ca; __sincosf(a, &sa, &ca);
    float4 th = ((const float4*)theta)[v];
    float4 gm = ((const float4*)gamma)[v];
    float thv[4] = {th.x, th.y, th.z, th.w};
    float cp[4];
    #pragma unroll
    for (int d = 0; d < 4; ++d) {
        float sth, cth; __sincosf(thv[d], &sth, &cth);
        float sf = fmaf(cth, sa,  sth * ca);  // sin(th + a), exact i-side
        float cf = fmaf(-sth, sa, cth * ca);  // cos(th + a)
        float sp = fmaf(-cth, sa, sth * ca);  // sin(th - a)
        float cq = fmaf(sth, sa,  cth * ca);  // cos(th - a)
        const float4* Hq = (const float4*)(lH + (c * 4 + d) * (NB * 8));
        float4 Plo = Hq[bb * 2];
        float4 Phi = Hq[bb * 2 + 1];
        float4 T   = Hq[(NB - 1) * 2 + 1];
        float lowS = fmaf(0.25f - a, Plo.x, Plo.z);
        float lowC = fmaf(0.25f - a, Plo.y, Plo.w);
        float lower = cf * lowS - sf * lowC;
        float S4 = T.x - Phi.x, S5 = T.y - Phi.y;
        float S6 = T.z - Phi.z, S7 = T.w - Phi.w;
        float upS = fmaf(0.25f + a, S4, -S6);
        float upC = fmaf(0.25f + a, S5, -S7);
        float upper = cq * upS - sp * upC;
        cp[d] = (lower + upper) * (1.0f / (float)NC);
    }
    float tx = gm.x + cp[0], ty = gm.y + cp[1];
    float tz = gm.z + cp[2], tw = gm.w + cp[3];
    float nrm = sqrtf(tx * tx + ty * ty + tz * tz + tw * tw);
    float inv = 1.0f / fmaxf(nrm, 1e-6f);
    ((float4*)out)[v] = make_float4(tx * inv, ty * inv, tz * inv, tw * inv);
}

extern "C" void kernel_launch(void* const* d_in, const int* in_sizes, int n_in,
                              void* d_out, int out_size, void* d_ws, size_t ws_size,
                              hipStream_t stream) {
    const float* theta  = (const float*)d_in[0];
    const float* gamma  = (const float*)d_in[1];
    const float* spikes = (const float*)d_in[2];
    float* out = (float*)d_out;
    float* ws  = (float*)d_ws;

    hipLaunchKernelGGL(k_hist,  dim3(BATCH * CPB),    dim3(256), 0, stream, spikes, theta, ws);
    hipLaunchKernelGGL(k_mscan, dim3(NG * 4),         dim3(256), 0, stream, ws);
    hipLaunchKernelGGL(k_apply, dim3(BATCH*NN/256),   dim3(256), 0, stream,
                       spikes, theta, gamma, ws, out);
}